// Round 13
// baseline (256.901 us; speedup 1.0000x reference)
//
#include <hip/hip_runtime.h>
#include <stdint.h>

#define ROWS   4096
#define NCOL   8192
#define TARGET 7680
#define NW     (NCOL - TARGET + 1)   // 513 windows
#define NT     64                    // ONE wave per block: zero barriers
#define NF4    (NCOL / 4 / NT)       // 32 float4 loads per lane
#define NB     2048                  // tail histogram bins (1024 per side)
#define BPL    (NB / NT)             // 32 bins per lane in scan
#define HALFB  (NB / 2)
#define SCAP   1536                  // candidate capacity (tot ~1372 on N(0,1))
#define MAXS   (SCAP / NT)           // 24 staged slots per lane

// Tail filter: only ranks [0,513) and [7679,8192) matter. P(|v|>1.38)=8.38%
// per side for N(0,1): E=686, sigma=25 -> clo,chi>=513 at 6.9 sigma and
// tot<=1536 at 4.7 sigma. Guard checks all three; fail -> exact fallback.
#define T_LO   (-1.38f)
#define T_HI   (1.38f)
#define BMIN   (-4.0f)
#define BSC    ((float)HALFB / (T_LO - BMIN))   // ~391 bins/unit, ~0.7 elem/bin

struct __align__(16) Smem {
    uint32_t hist[NB];    // 8 KB
    float    buf[SCAP];   // 6 KB: queue -> scattered -> sorted (in-place)
};
// 14.3 KB/block, 1 wave/block -> 11 independent waves per CU, no syncthreads.

// transposed phys index: lane owns bins [32*lane,32*lane+32); scan reads
// hist[(j<<6)|lane] lane-consecutively (conflict-free); atomics hash on
// bin bits 5..10 (random for data-dependent bins).
__device__ __forceinline__ int HIX(int b) { return ((b & 31) << 6) | (b >> 5); }

// fast-path tail map (caller guarantees v<T_LO or v>T_HI); monotone, clamped.
__device__ __forceinline__ int fbin(float v) {
    if (v < T_LO) {
        int b = (int)((v - BMIN) * BSC);
        b = b < 0 ? 0 : b;
        return b > HALFB - 1 ? HALFB - 1 : b;
    }
    int b = (int)((v - T_HI) * BSC);
    b = b < 0 ? 0 : b;
    b = b > HALFB - 1 ? HALFB - 1 : b;
    return HALFB + b;
}
// fallback dynamic full-range map
__device__ __forceinline__ int dbin(float v, float mn, float s) {
    int b = (int)((v - mn) * s);
    b = b < 0 ? 0 : b;
    return b > NB - 1 ? NB - 1 : b;
}

__global__ __launch_bounds__(NT, 4)
void recall_window_kernel(const float* __restrict__ x, float* __restrict__ out) {
    __shared__ Smem sm;
    const int lane = threadIdx.x;        // block == one wave
    const int row  = blockIdx.x;
    const float4* xv = (const float4*)(x + (size_t)row * NCOL);
    const uint64_t below = (1ull << lane) - 1ull;

    // ---- zero hist (8 x b128, conflict-free) ----
    #pragma unroll
    for (int j = 0; j < NB / 4 / NT; j++) {
        uint4 z; z.x = 0; z.y = 0; z.z = 0; z.w = 0;
        *(uint4*)&sm.hist[4 * (j * NT + lane)] = z;
    }

    // ---- single stream pass: tail-compact into LDS queue via ballot.
    //      Queue counter is a wave-uniform register -- NO atomics ----
    uint32_t qc = 0, clo = 0, chi = 0;
    #pragma unroll
    for (int q = 0; q < NF4; q++) {
        float4 t = xv[lane + q * NT];
        #pragma unroll
        for (int c = 0; c < 4; c++) {
            float v = c == 0 ? t.x : c == 1 ? t.y : c == 2 ? t.z : t.w;
            uint64_t mlo = __ballot(v < T_LO);
            uint64_t mhi = __ballot(v > T_HI);
            uint64_t m   = mlo | mhi;
            if (m & (1ull << lane)) {
                uint32_t off = qc + (uint32_t)__popcll(m & below);
                if (off < SCAP) sm.buf[off] = v;
            }
            qc  += (uint32_t)__popcll(m);
            clo += (uint32_t)__popcll(mlo);
            chi += (uint32_t)__popcll(mhi);
        }
    }

    if (clo >= NW && chi >= NW && qc <= SCAP) {   // wave-uniform fast path
        // ---- stage queue to registers (all reads precede all writes:
        //      wave lockstep makes in-place safe with no barrier) ----
        float qv[MAXS];
        #pragma unroll
        for (int it = 0; it < MAXS; it++) {
            int s = lane + it * NT;
            qv[it] = (s < (int)qc) ? sm.buf[s] : 0.f;
        }
        // ---- hist candidates only (~22 dense atomic instrs) ----
        #pragma unroll
        for (int it = 0; it < MAXS; it++) {
            int s = lane + it * NT;
            if (s < (int)qc) atomicAdd(&sm.hist[HIX(fbin(qv[it]))], 1u);
        }
        // ---- in-wave scan (shfl only; bottom bins precede top bins, so
        //      bases give ranks directly: no rank-locate, no shiftT) ----
        uint32_t h[BPL], s0 = 0;
        #pragma unroll
        for (int j = 0; j < BPL; j++) { h[j] = sm.hist[(j << 6) | lane]; s0 += h[j]; }
        uint32_t sc = s0;
        #pragma unroll
        for (int off = 1; off < 64; off <<= 1) {
            uint32_t n = __shfl_up(sc, off, 64);
            if (lane >= off) sc += n;
        }
        uint32_t run = sc - s0;
        #pragma unroll
        for (int j = 0; j < BPL; j++) { sm.hist[(j << 6) | lane] = run; run += h[j]; }
        // ---- scatter from staged regs, in-place into buf ----
        #pragma unroll
        for (int it = 0; it < MAXS; it++) {
            int s = lane + it * NT;
            if (s < (int)qc) {
                int b = fbin(qv[it]);
                uint32_t pos = atomicAdd(&sm.hist[HIX(b)], 1u);
                sm.buf[pos] = qv[it];            // pos < qc <= SCAP (all appended)
            }
        }
        // ---- fixup: rank within bin; stage all reads, then write back ----
        float sv[MAXS]; int tg[MAXS];
        #pragma unroll
        for (int it = 0; it < MAXS; it++) {
            int s = lane + it * NT; tg[it] = -1;
            if (s < (int)qc) {
                float vv = sm.buf[s];
                int b = fbin(vv);
                uint32_t en = sm.hist[HIX(b)];
                uint32_t st = (b == 0) ? 0u : sm.hist[HIX(b - 1)];
                uint32_t r = 0;
                if (en - st > 1) {
                    for (uint32_t p = st; p < en; p++) {
                        float u = sm.buf[p];
                        r += (u < vv) || (u == vv && (int)p < s);
                    }
                }
                tg[it] = (int)(st + r); sv[it] = vv;
            }
        }
        #pragma unroll
        for (int it = 0; it < MAXS; it++)
            if (tg[it] >= 0) sm.buf[tg[it]] = sv[it];

        // buf[0..clo) = ranks 0..clo-1; buf[clo..qc) = ranks 8192-chi..8191.
        // window i: left = buf[i]; right = rank 7679+i -> slot qc-513+i.
        const int topstart = (int)qc - NW;
        float lbest = __int_as_float(0x7F800000);
        int   lidx  = 0x7FFFFFFF;
        for (int i = lane; i < NW; i += NT) {
            float len = sm.buf[topstart + i] - sm.buf[i];
            if (len < lbest) { lbest = len; lidx = i; }
        }
        #pragma unroll
        for (int off = 32; off > 0; off >>= 1) {
            float v2 = __shfl_down(lbest, off, 64);
            int   i2 = __shfl_down(lidx,  off, 64);
            if (v2 < lbest || (v2 == lbest && i2 < lidx)) { lbest = v2; lidx = i2; }
        }
        if (lane == 0) {
            out[row]        = sm.buf[lidx];
            out[ROWS + row] = sm.buf[topstart + lidx];
        }
        return;
    }

    // ======== FALLBACK: exact per-wave dynamic path (rare) ========
    // hist is still all-zero (fast path built it only inside the guard).
    float mn = __int_as_float(0x7F800000), mx = -mn;
    #pragma unroll
    for (int q = 0; q < NF4; q++) {
        float4 t = xv[lane + q * NT];
        mn = fminf(mn, fminf(fminf(t.x, t.y), fminf(t.z, t.w)));
        mx = fmaxf(mx, fmaxf(fmaxf(t.x, t.y), fmaxf(t.z, t.w)));
    }
    #pragma unroll
    for (int off = 1; off < 64; off <<= 1) {   // butterfly: all lanes get result
        mn = fminf(mn, __shfl_xor(mn, off, 64));
        mx = fmaxf(mx, __shfl_xor(mx, off, 64));
    }
    if (!(mx > mn)) {   // all values equal
        if (lane == 0) { out[row] = mn; out[ROWS + row] = mn; }
        return;
    }
    const float amn = mn, asc = (float)NB / (mx - mn);

    #pragma unroll
    for (int q = 0; q < NF4; q++) {   // hist all values
        float4 t = xv[lane + q * NT];
        atomicAdd(&sm.hist[HIX(dbin(t.x, amn, asc))], 1u);
        atomicAdd(&sm.hist[HIX(dbin(t.y, amn, asc))], 1u);
        atomicAdd(&sm.hist[HIX(dbin(t.z, amn, asc))], 1u);
        atomicAdd(&sm.hist[HIX(dbin(t.w, amn, asc))], 1u);
    }
    // scan + register-broadcast rank-locate (no LDS res[], no barrier)
    uint32_t h[BPL], s0 = 0;
    #pragma unroll
    for (int j = 0; j < BPL; j++) { h[j] = sm.hist[(j << 6) | lane]; s0 += h[j]; }
    uint32_t sc = s0;
    #pragma unroll
    for (int off = 1; off < 64; off <<= 1) {
        uint32_t n = __shfl_up(sc, off, 64);
        if (lane >= off) sc += n;
    }
    const uint32_t excl = sc - s0;
    const uint32_t ka = NW - 1, kb = TARGET - 1;
    uint32_t encA = 0xFFFFFFFFu, encB = 0xFFFFFFFFu;   // (bin<<14)|count
    {
        uint32_t c = excl;
        #pragma unroll
        for (int j = 0; j < BPL; j++) {
            if (ka >= c && ka < c + h[j]) encA = ((uint32_t)(lane * BPL + j) << 14) | (c + h[j]);
            if (kb >= c && kb < c + h[j]) encB = ((uint32_t)(lane * BPL + j) << 14) | c;
            c += h[j];
        }
    }
    #pragma unroll
    for (int off = 1; off < 64; off <<= 1) {
        uint32_t a2 = __shfl_xor(encA, off, 64); encA = a2 < encA ? a2 : encA;
        uint32_t b2 = __shfl_xor(encB, off, 64); encB = b2 < encB ? b2 : encB;
    }
    const int      B_lo    = (int)(encA >> 14);
    const uint32_t cntB    = encA & 0x3FFFu;
    const int      B_hi    = (int)(encB >> 14);
    const uint32_t topBase = encB & 0x3FFFu;
    const uint32_t shiftT  = cntB - topBase;           // mod-2^32
    uint32_t tot = cntB + (uint32_t)NCOL - topBase;
    if (tot > SCAP) tot = SCAP;                        // dup-heavy clamp parity
    {
        uint32_t run = excl;
        #pragma unroll
        for (int j = 0; j < BPL; j++) { sm.hist[(j << 6) | lane] = run; run += h[j]; }
    }
    // scatter: re-stream the row
    #pragma unroll
    for (int q = 0; q < NF4; q++) {
        float4 t = xv[lane + q * NT];
        #pragma unroll
        for (int c = 0; c < 4; c++) {
            float v = c == 0 ? t.x : c == 1 ? t.y : c == 2 ? t.z : t.w;
            int b = dbin(v, amn, asc);
            if (b <= B_lo || b >= B_hi) {
                uint32_t pos = atomicAdd(&sm.hist[HIX(b)], 1u);
                if (b >= B_hi) pos += shiftT;
                if (pos < SCAP) sm.buf[pos] = v;
            }
        }
    }
    // fixup staged, in-place
    float sv[MAXS]; int tg[MAXS];
    #pragma unroll
    for (int it = 0; it < MAXS; it++) {
        int s = lane + it * NT; tg[it] = -1;
        if (s < (int)tot) {
            float vv = sm.buf[s];
            int b = dbin(vv, amn, asc);
            uint32_t en = sm.hist[HIX(b)];
            uint32_t st;
            if (s < (int)cntB) {
                st = (b == 0) ? 0u : sm.hist[HIX(b - 1)];
            } else {
                st = (b == B_hi) ? topBase : sm.hist[HIX(b - 1)];
                st += shiftT; en += shiftT;
            }
            if (en > tot) en = tot;
            uint32_t r = 0;
            if (en - st > 1) {
                for (uint32_t p = st; p < en; p++) {
                    float u = sm.buf[p];
                    r += (u < vv) || (u == vv && (int)p < s);
                }
            }
            uint32_t d = st + r;
            if (d < SCAP) { tg[it] = (int)d; sv[it] = vv; }
        }
    }
    #pragma unroll
    for (int it = 0; it < MAXS; it++)
        if (tg[it] >= 0) sm.buf[tg[it]] = sv[it];

    const int topstart = (int)tot - NW;
    float lbest = __int_as_float(0x7F800000);
    int   lidx  = 0x7FFFFFFF;
    for (int i = lane; i < NW; i += NT) {
        float len = sm.buf[topstart + i] - sm.buf[i];
        if (len < lbest) { lbest = len; lidx = i; }
    }
    #pragma unroll
    for (int off = 32; off > 0; off >>= 1) {
        float v2 = __shfl_down(lbest, off, 64);
        int   i2 = __shfl_down(lidx,  off, 64);
        if (v2 < lbest || (v2 == lbest && i2 < lidx)) { lbest = v2; lidx = i2; }
    }
    if (lane == 0) {
        out[row]        = sm.buf[lidx];
        out[ROWS + row] = sm.buf[topstart + lidx];
    }
}

extern "C" void kernel_launch(void* const* d_in, const int* in_sizes, int n_in,
                              void* d_out, int out_size, void* d_ws, size_t ws_size,
                              hipStream_t stream) {
    const float* x = (const float*)d_in[0];
    float* out = (float*)d_out;
    recall_window_kernel<<<ROWS, NT, 0, stream>>>(x, out);
}